// Round 10
// baseline (144.051 us; speedup 1.0000x reference)
//
#include <hip/hip_runtime.h>

// Conv2d int32 (values fit int8) via implicit GEMM, v16: fat tile + tap pipeline.
// x8: [chunk8][b16][row58][slot58][32B] (halo zeroed, granule parity (g+(slot>>2))&1)
// w8: [cotile4][chunk8][co64][tap9][32B] (granule parity (g+(co>>2))&1)
// v16 = v10's co-128x64px geometry (ratio 16 MFMA / 8 reads = 2.0 -> LDS
// demand 66% of MFMA demand, matrix pipe sole critical path) + the v12/v13
// machinery v10 lacked: fa/fb double-buffered tap pipeline with SGB
// {DS_READ 8, MFMA 16} (tap t+1 reads issue under tap t's 586-cyc MFMA burst)
// and v13's stage-after-barrier / drain-before-barrier chunk loop.
// 256 thr / 4 waves, each co-128 x 2 rows; grid (112,2)=224, 1 block/CU,
// __launch_bounds__(256,1): ~380 regs used of 512 -> no spill (v10 suspect).
// Rationale: at acc[2][4] the read/MFMA ratio exactly saturates the LDS pipe
// share (48cyc/read demand vs 48 capacity) -> scheduling can't win; v13/v15
// levers all null. Only intensity helps.

typedef int v4i  __attribute__((ext_vector_type(4)));
typedef int v16i __attribute__((ext_vector_type(16)));

#define X8_ROWSTRIDE 1856                 // 58 slots * 32 B
#define X8_IMGSTRIDE 107648               // 58 rows * 1856
#define X8_BYTES     13778944             // 128 images (8 chunks x 16 b)
#define W8_CHUNK     18432                // 64 co * 9 tap * 32 B
#define W8_COTILE    147456               // 8 chunks * W8_CHUNK
#define WBUF         36864                // cotile-pair chunk (128 co)
#define XBUF         20480                // 10 rows (18,560 B) + pad
#define LBUF         57344                // WBUF + XBUF

typedef const __attribute__((address_space(1))) unsigned char* gptr_t;
typedef __attribute__((address_space(3))) unsigned char* lptr_t;

__device__ __forceinline__ void gll(const unsigned char* g, unsigned char* l) {
  __builtin_amdgcn_global_load_lds((gptr_t)g, (lptr_t)l, 16, 0, 0);
}

__device__ __forceinline__ int pack4(const int* p, int stride) {
  return (p[0] & 255) | ((p[stride] & 255) << 8) |
         ((p[2 * stride] & 255) << 16) | ((p[3 * stride] & 255) << 24);
}

// ---- fused prepass (identical to v9/v13/v15) ----
__global__ __launch_bounds__(256)
void pack_all(const int* __restrict__ x, const int* __restrict__ wgt,
              unsigned char* __restrict__ ws8) {
  const int blk = blockIdx.x;
  if (blk < 784) {
    const int gid = blk * 256 + threadIdx.x;
    const int srcg = gid & 1;
    int t = gid >> 1;
    const int sq = t % 14;  t /= 14;      // slots 4sq+1 .. 4sq+4, iw 4sq .. 4sq+3
    const int row = t % 56 + 1;           // 1..56
    const int cb  = t / 56;               // chunk*16 + b
    const int chunk = cb >> 4, b = cb & 15;
    const int ci0 = chunk * 32 + srcg * 16;
    const int* src = x + (b * 256 + ci0) * 3136 + (row - 1) * 56 + 4 * sq;
    v4i L[16];
    #pragma unroll
    for (int ch = 0; ch < 16; ++ch) L[ch] = *(const v4i*)(src + ch * 3136);
    unsigned char* dstrow = ws8 + cb * X8_IMGSTRIDE + row * X8_ROWSTRIDE;
    #pragma unroll
    for (int j = 0; j < 4; ++j) {
      const int slot = 4 * sq + 1 + j;
      v4i g;
      #pragma unroll
      for (int d = 0; d < 4; ++d)
        g[d] = (L[4 * d][j] & 255) | ((L[4 * d + 1][j] & 255) << 8) |
               ((L[4 * d + 2][j] & 255) << 16) | ((L[4 * d + 3][j] & 255) << 24);
      const int p = (srcg + (slot >> 2)) & 1;   // inverse of srcg=(p+(slot>>2))&1
      *(v4i*)(dstrow + slot * 32 + p * 16) = g;
    }
  } else if (blk < 1012) {
    const int g2 = (blk - 784) * 256 + threadIdx.x;   // 58,368 granules
    const int cb = g2 / 456;
    const int r  = g2 - cb * 456;
    int off;
    if (r < 232) {                       // rows 0 and 57, all 58 slots x 2 granules
      const int row = r < 116 ? 0 : 57;
      const int rr = r % 116;
      off = row * X8_ROWSTRIDE + (rr >> 1) * 32 + (rr & 1) * 16;
    } else {                             // rows 1..56, slots 0 and 57
      const int r2 = r - 232;            // 0..223
      const int row = (r2 >> 2) + 1;
      const int slot = (r2 & 2) ? 57 : 0;
      off = row * X8_ROWSTRIDE + slot * 32 + (r2 & 1) * 16;
    }
    *(v4i*)(ws8 + cb * X8_IMGSTRIDE + off) = (v4i){0, 0, 0, 0};
  } else {
    const int gw = (blk - 1012) * 256 + threadIdx.x;  // 36,864 granules exact
    const int p = gw & 1;
    int t = gw >> 1;
    const int tap = t % 9;  t /= 9;
    const int co = t & 63;
    const int tcc = t >> 6;              // 0..287: chunk 0..7, cotile 0..3
    const int chunk = tcc & 7, cotile = tcc >> 3;
    const int srcg = (p + (co >> 2)) & 1;   // inverse of p=(srcg+(co>>2))&1
    const int ci0 = chunk * 32 + srcg * 16;
    const int* src = wgt + ((cotile * 64 + co) * 256 + ci0) * 9 + tap;
    v4i v = (v4i){pack4(src, 9), pack4(src + 36, 9),
                  pack4(src + 72, 9), pack4(src + 108, 9)};
    *(v4i*)(ws8 + X8_BYTES + (t * 9 + tap) * 32 + p * 16) = v;
  }
}

// ---- stage one chunk for a cotile-pair block: w 36,864 B + x 20,480 B ----
// 3,584 granules / 256 threads = exactly 14 gll per thread, wave-uniform
// splits (tid<128 = waves 0-1).
__device__ __forceinline__ void stage_chunk(const unsigned char* wa,
                                            const unsigned char* wb,
                                            const unsigned char* xg,
                                            unsigned char* ldsb, int c, int buf,
                                            int tid) {
  const unsigned char* wsa = wa + c * W8_CHUNK;
  const unsigned char* wsb = wb + c * W8_CHUNK;
  const unsigned char* xsrc = xg + c * (16 * X8_IMGSTRIDE);
  unsigned char* wdst = ldsb + buf * LBUF;
  unsigned char* xdst = wdst + WBUF;
  #pragma unroll
  for (int i = 0; i < 4; ++i) {          // cotile-A granules [0,1024)
    const int o = (tid + i * 256) * 16;
    gll(wsa + o, wdst + o);
  }
  if (tid < 128) {                       // cotile-A granules [1024,1152)
    const int o = (1024 + tid) * 16;
    gll(wsa + o, wdst + o);
  } else {                               // cotile-B granules [0,128)
    const int o = (tid - 128) * 16;
    gll(wsb + o, wdst + W8_CHUNK + o);
  }
  #pragma unroll
  for (int i = 0; i < 4; ++i) {          // cotile-B granules [128,1152)
    const int o = (128 + tid + i * 256) * 16;
    gll(wsb + o, wdst + W8_CHUNK + o);
  }
  #pragma unroll
  for (int i = 0; i < 5; ++i) {          // x granules [0,1280) = 20,480 B
    const int o = (tid + i * 256) * 16;  // rows h0..h0+9 staged (+pad, unread)
    gll(xsrc + o, xdst + o);
  }
}

// Load fragment set for tap T (compile-time after unroll) into slot S.
// 8 ds_read_b128: fa[S][q] (q*9216: A co0-31/32-63, B co0-31/32-63), fb[S][bt].
#define LOADTAP(T, S)                                                     \
  do {                                                                    \
    const int kh_ = (T) / 3, kw_ = (T) % 3;                               \
    const unsigned char* xr_ = xs + rbase + kh_ * X8_ROWSTRIDE;           \
    fa[S][0] = *(const v4i*)(wls + 0 * 9216 + abase + (T) * 32);          \
    fa[S][1] = *(const v4i*)(wls + 1 * 9216 + abase + (T) * 32);          \
    fa[S][2] = *(const v4i*)(wls + 2 * 9216 + abase + (T) * 32);          \
    fa[S][3] = *(const v4i*)(wls + 3 * 9216 + abase + (T) * 32);          \
    fb[S][0] = *(const v4i*)(xr_ + boff[kw_][0]);                         \
    fb[S][1] = *(const v4i*)(xr_ + boff[kw_][1]);                         \
    fb[S][2] = *(const v4i*)(xr_ + boff[kw_][2]);                         \
    fb[S][3] = *(const v4i*)(xr_ + boff[kw_][3]);                         \
  } while (0)

// ---- main kernel: co-128 per wave, acc[4][4], tap pipeline, 1 block/CU ----
__global__ __launch_bounds__(256, 1)
void conv_main(const unsigned char* __restrict__ ws8, const int* __restrict__ bias,
               int* __restrict__ out) {
  __shared__ __align__(16) unsigned char lds[2 * LBUF];   // 114,688 B
  __shared__ int bls[128];

  const int tid = threadIdx.x, lane = tid & 63, wv = tid >> 6;  // wv 0..3
  const int n = lane & 31, gq = lane >> 5;
  const int tc = blockIdx.y;             // co tile of 128 (0..1)
  const int hb = blockIdx.x;             // hg*16 + b
  const int hg = hb >> 4, b = hb & 15;   // hg 0..6
  const int h0 = hg * 8;

  if (tid < 128) bls[tid] = bias[tc * 128 + tid];
  asm volatile("s_waitcnt lgkmcnt(0)" ::: "memory");

  const int abase = n * 288 + (((gq + (n >> 2)) & 1) << 4);
  int boff[3][4];
  #pragma unroll
  for (int kw = 0; kw < 3; ++kw)
    #pragma unroll
    for (int bt = 0; bt < 4; ++bt) {
      int slot = bt * 16 + (n & 15) + kw;
      if (slot > 57) slot = 57;
      boff[kw][bt] = slot * 32 + (((gq + (slot >> 2)) & 1) << 4);
    }
  const int rbase = (2 * wv + (n >> 4)) * X8_ROWSTRIDE;   // rows 0..7 of stage

  v16i acc[4][4];
  #pragma unroll
  for (int i = 0; i < 4; ++i)
    #pragma unroll
    for (int j = 0; j < 4; ++j)
      acc[i][j] = (v16i){0,0,0,0,0,0,0,0,0,0,0,0,0,0,0,0};

  const unsigned char* wa = ws8 + X8_BYTES + (2 * tc) * W8_COTILE;
  const unsigned char* wb = wa + W8_COTILE;
  const unsigned char* xg = ws8 + b * X8_IMGSTRIDE + h0 * X8_ROWSTRIDE;

  stage_chunk(wa, wb, xg, lds, 0, 0, tid);
  int buf = 0;
  #pragma unroll 1
  for (int c = 0; c < 8; ++c) {
    // stage(c) was issued one chunk of compute ago (except c=0) -> near-free.
    asm volatile("s_waitcnt vmcnt(0)" ::: "memory");
    __builtin_amdgcn_s_barrier();
    asm volatile("" ::: "memory");
    if (c < 7) stage_chunk(wa, wb, xg, lds, c + 1, buf ^ 1, tid);
    {
      const unsigned char* wls = lds + buf * LBUF;
      const unsigned char* xs  = wls + WBUF;
      v4i fa[2][4], fb[2][4];
      LOADTAP(0, 0);                      // preload tap 0
      __builtin_amdgcn_sched_group_barrier(0x100, 8, 0);   // DS_READ x8 (tap 0)
      #pragma unroll
      for (int tap = 0; tap < 9; ++tap) {
        const int cur = tap & 1, nxt = cur ^ 1;
        if (tap < 8) {
          LOADTAP(tap + 1, nxt);          // issue next-tap reads FIRST
          __builtin_amdgcn_sched_group_barrier(0x100, 8, 0); // DS_READ x8 (t+1)
        }
        #pragma unroll
        for (int q = 0; q < 4; ++q)
          #pragma unroll
          for (int bt = 0; bt < 4; ++bt)
            acc[q][bt] = __builtin_amdgcn_mfma_i32_32x32x32_i8(fa[cur][q], fb[cur][bt], acc[q][bt], 0, 0, 0);
        __builtin_amdgcn_sched_group_barrier(0x008, 16, 0);  // MFMA x16 (tap t)
      }
    }
    buf ^= 1;
  }

  const int h = h0 + 2 * wv + (n >> 4);   // <= 55 always
  const int wbase = lane & 15;
  #pragma unroll
  for (int q = 0; q < 4; ++q) {
    #pragma unroll
    for (int r = 0; r < 16; ++r) {
      const int co = q * 32 + (r & 3) + 8 * (r >> 2) + 4 * gq;   // 0..127
      const int bv = bls[co];
      int* orow = out + ((b * 256 + tc * 128 + co) * 56 + h) * 56;
      #pragma unroll
      for (int bt = 0; bt < 4; ++bt) {
        const int w0 = bt * 16 + wbase;
        if (w0 < 56) orow[w0] = acc[q][bt][r] + bv;
      }
    }
  }
}

extern "C" void kernel_launch(void* const* d_in, const int* in_sizes, int n_in,
                              void* d_out, int out_size, void* d_ws, size_t ws_size,
                              hipStream_t stream) {
  const int* x    = (const int*)d_in[0];
  const int* w    = (const int*)d_in[1];
  const int* bias = (const int*)d_in[2];
  unsigned char* ws8 = (unsigned char*)d_ws;   // x8 then w8 (~14.4 MB)
  hipLaunchKernelGGL(pack_all, dim3(1156), dim3(256), 0, stream, x, w, ws8);
  hipLaunchKernelGGL(conv_main, dim3(112, 2, 1), dim3(256), 0, stream,
                     ws8, bias, (int*)d_out);
}

// Round 11
// 129.868 us; speedup vs baseline: 1.1092x; 1.1092x over previous
//
#include <hip/hip_runtime.h>

// Conv2d int32 (values fit int8) via implicit GEMM, v17: 16-lane-phase swizzle fix.
// x8: [chunk8][b16][row58][slot58][32B] (halo zeroed, granule parity (g+(slot>>3))&1)
// w8: [cotile4][chunk8][co64][tap9][32B] (granule parity (g+(co>>3))&1)
// v17 = v13 (best, 130.16us) with ONLY the parity-swizzle bit changed from
// (slot>>2)/(co>>2) to (slot>>3)/(co>>3). Evidence: SQ_LDS_BANK_CONFLICT =
// 2,064,384 = 5.33 extra cyc per ds_read_b128 in v13; bank algebra at
// 16-lane phase width (addr/16 = 2*slot + par) shows lanes i and i+8 collide
// whenever par has period <8 in slot — true for both v8's (slot) and v9's
// (slot>>2). par=(slot>>3) makes all 16 lanes of a phase hit distinct
// addr/16 mod 16. Same algebra for A reads (18n + par, par=(n>>3)).
// Correctness: write/read parity is (a+b)&1 = XOR, both sides changed
// together -> bijection preserved; halo slots zero both granules.
// v16 post-mortem: fat tile (co-128/wave, 1 wave/SIMD) failed twice
// (60us, 78us, VGPR=256 cap) -> geometry abandoned.

typedef int v4i  __attribute__((ext_vector_type(4)));
typedef int v16i __attribute__((ext_vector_type(16)));

#define X8_ROWSTRIDE 1856                 // 58 slots * 32 B
#define X8_IMGSTRIDE 107648               // 58 rows * 1856
#define X8_BYTES     13778944             // 128 images (8 chunks x 16 b)
#define W8_CHUNK     18432                // 64 co * 9 tap * 32 B
#define WBUF         18432
#define XBUF         20480                // 1,280 granules (10 rows used = 1,160)
#define LBUF         38912                // WBUF + XBUF

typedef const __attribute__((address_space(1))) unsigned char* gptr_t;
typedef __attribute__((address_space(3))) unsigned char* lptr_t;

__device__ __forceinline__ void gll(const unsigned char* g, unsigned char* l) {
  __builtin_amdgcn_global_load_lds((gptr_t)g, (lptr_t)l, 16, 0, 0);
}

__device__ __forceinline__ int pack4(const int* p, int stride) {
  return (p[0] & 255) | ((p[stride] & 255) << 8) |
         ((p[2 * stride] & 255) << 16) | ((p[3 * stride] & 255) << 24);
}

// ---- fused prepass (v13 with parity>>3) ----
__global__ __launch_bounds__(256)
void pack_all(const int* __restrict__ x, const int* __restrict__ wgt,
              unsigned char* __restrict__ ws8) {
  const int blk = blockIdx.x;
  if (blk < 784) {
    const int gid = blk * 256 + threadIdx.x;
    const int srcg = gid & 1;
    int t = gid >> 1;
    const int sq = t % 14;  t /= 14;      // slots 4sq+1 .. 4sq+4, iw 4sq .. 4sq+3
    const int row = t % 56 + 1;           // 1..56
    const int cb  = t / 56;               // chunk*16 + b
    const int chunk = cb >> 4, b = cb & 15;
    const int ci0 = chunk * 32 + srcg * 16;
    const int* src = x + (b * 256 + ci0) * 3136 + (row - 1) * 56 + 4 * sq;
    v4i L[16];
    #pragma unroll
    for (int ch = 0; ch < 16; ++ch) L[ch] = *(const v4i*)(src + ch * 3136);
    unsigned char* dstrow = ws8 + cb * X8_IMGSTRIDE + row * X8_ROWSTRIDE;
    #pragma unroll
    for (int j = 0; j < 4; ++j) {
      const int slot = 4 * sq + 1 + j;
      v4i g;
      #pragma unroll
      for (int d = 0; d < 4; ++d)
        g[d] = (L[4 * d][j] & 255) | ((L[4 * d + 1][j] & 255) << 8) |
               ((L[4 * d + 2][j] & 255) << 16) | ((L[4 * d + 3][j] & 255) << 24);
      const int p = (srcg + (slot >> 3)) & 1;   // inverse of srcg=(p+(slot>>3))&1
      *(v4i*)(dstrow + slot * 32 + p * 16) = g;
    }
  } else if (blk < 1012) {
    const int g2 = (blk - 784) * 256 + threadIdx.x;   // 58,368 granules
    const int cb = g2 / 456;
    const int r  = g2 - cb * 456;
    int off;
    if (r < 232) {                       // rows 0 and 57, all 58 slots x 2 granules
      const int row = r < 116 ? 0 : 57;
      const int rr = r % 116;
      off = row * X8_ROWSTRIDE + (rr >> 1) * 32 + (rr & 1) * 16;
    } else {                             // rows 1..56, slots 0 and 57
      const int r2 = r - 232;            // 0..223
      const int row = (r2 >> 2) + 1;
      const int slot = (r2 & 2) ? 57 : 0;
      off = row * X8_ROWSTRIDE + slot * 32 + (r2 & 1) * 16;
    }
    *(v4i*)(ws8 + cb * X8_IMGSTRIDE + off) = (v4i){0, 0, 0, 0};
  } else {
    const int gw = (blk - 1012) * 256 + threadIdx.x;  // 36,864 granules exact
    const int p = gw & 1;
    int t = gw >> 1;
    const int tap = t % 9;  t /= 9;
    const int co = t & 63;
    const int tcc = t >> 6;              // 0..287: chunk 0..7, cotile 0..3
    const int chunk = tcc & 7, cotile = tcc >> 3;
    const int srcg = (p + (co >> 3)) & 1;   // inverse of p=(srcg+(co>>3))&1
    const int ci0 = chunk * 32 + srcg * 16;
    const int* src = wgt + ((cotile * 64 + co) * 256 + ci0) * 9 + tap;
    v4i v = (v4i){pack4(src, 9), pack4(src + 36, 9),
                  pack4(src + 72, 9), pack4(src + 108, 9)};
    *(v4i*)(ws8 + X8_BYTES + (t * 9 + tap) * 32 + p * 16) = v;
  }
}

// ---- stage one chunk (w 18,432 B + x 20,480 B = 2,432 granules) into buf ----
__device__ __forceinline__ void stage_chunk(const unsigned char* wg,
                                            const unsigned char* xg,
                                            unsigned char* ldsb, int c, int buf,
                                            int tid) {
  const unsigned char* wsrc = wg + c * W8_CHUNK;
  const unsigned char* xsrc = xg + c * (16 * X8_IMGSTRIDE);
  unsigned char* wdst = ldsb + buf * LBUF;
  unsigned char* xdst = wdst + WBUF;
  #pragma unroll
  for (int i = 0; i < 4; ++i) {          // w granules [0,1024)
    const int o = (tid + i * 256) * 16;
    gll(wsrc + o, wdst + o);
  }
  if (tid < 128) {                       // w granules [1024,1152)
    const int o = (1024 + tid) * 16;
    gll(wsrc + o, wdst + o);
  } else {                               // x granules [0,128)
    const int o = (tid - 128) * 16;
    gll(xsrc + o, xdst + o);
  }
  #pragma unroll
  for (int i = 5; i < 9; ++i) {          // x granules [128,1152)
    const int o = (tid + i * 256 - 1152) * 16;
    gll(xsrc + o, xdst + o);
  }
  if (tid < 128) {                       // x granules [1152,1280)
    const int o = (1152 + tid) * 16;
    gll(xsrc + o, xdst + o);
  }
}

// Load fragment set for tap T (compile-time after unroll) into slot S.
#define LOADTAP(T, S)                                                     \
  do {                                                                    \
    const int kh_ = (T) / 3, kw_ = (T) % 3;                               \
    const unsigned char* xr_ = xs + rbase + kh_ * X8_ROWSTRIDE;           \
    fa0[S] = *(const v4i*)(wls + abase + (T) * 32);                       \
    fa1[S] = *(const v4i*)(wls + 9216 + abase + (T) * 32);                \
    fb[S][0] = *(const v4i*)(xr_ + boff[kw_][0]);                         \
    fb[S][1] = *(const v4i*)(xr_ + boff[kw_][1]);                         \
    fb[S][2] = *(const v4i*)(xr_ + boff[kw_][2]);                         \
    fb[S][3] = *(const v4i*)(xr_ + boff[kw_][3]);                         \
  } while (0)

// ---- main kernel: 4 waves, 64 co x 8 rows, 2 buffers, 2 blocks/CU ----
__global__ __launch_bounds__(256, 2)
void conv_main(const unsigned char* __restrict__ ws8, const int* __restrict__ bias,
               int* __restrict__ out) {
  __shared__ __align__(16) unsigned char lds[2 * LBUF];   // 77,824 B
  __shared__ int bls[64];

  const int tid = threadIdx.x, lane = tid & 63, wv = tid >> 6;  // wv 0..3
  const int n = lane & 31, gq = lane >> 5;
  const int tc = blockIdx.y;             // co tile of 64
  const int hb = blockIdx.x;             // hg*16 + b
  const int hg = hb >> 4, b = hb & 15;   // hg 0..6
  const int h0 = hg * 8;

  if (tid < 64) {
    bls[tid] = bias[tc * 64 + tid];
    asm volatile("s_waitcnt lgkmcnt(0)" ::: "memory");
  }

  const int abase = n * 288 + (((gq + (n >> 3)) & 1) << 4);
  int boff[3][4];
  #pragma unroll
  for (int kw = 0; kw < 3; ++kw)
    #pragma unroll
    for (int bt = 0; bt < 4; ++bt) {
      int slot = bt * 16 + (n & 15) + kw;
      if (slot > 57) slot = 57;
      boff[kw][bt] = slot * 32 + (((gq + (slot >> 3)) & 1) << 4);
    }
  const int rbase = (2 * wv + (n >> 4)) * X8_ROWSTRIDE;   // rows 0..7 of stage

  v16i acc[2][4];
  #pragma unroll
  for (int i = 0; i < 2; ++i)
    #pragma unroll
    for (int j = 0; j < 4; ++j)
      acc[i][j] = (v16i){0,0,0,0,0,0,0,0,0,0,0,0,0,0,0,0};

  const unsigned char* wg = ws8 + X8_BYTES + tc * (8 * W8_CHUNK);
  const unsigned char* xg = ws8 + b * X8_IMGSTRIDE + h0 * X8_ROWSTRIDE;

  stage_chunk(wg, xg, lds, 0, 0, tid);
  int buf = 0;
  #pragma unroll 1
  for (int c = 0; c < 8; ++c) {
    // stage(c) was issued before the previous barrier; latency hid under
    // compute(c-1), so this drain is near-free.
    asm volatile("s_waitcnt vmcnt(0)" ::: "memory");
    __builtin_amdgcn_s_barrier();
    asm volatile("" ::: "memory");
    if (c < 7) stage_chunk(wg, xg, lds, c + 1, buf ^ 1, tid);  // overlaps compute(c)
    {
      const unsigned char* wls = lds + buf * LBUF;
      const unsigned char* xs  = wls + WBUF;
      v4i fa0[2], fa1[2], fb[2][4];
      LOADTAP(0, 0);                      // preload tap 0
      __builtin_amdgcn_sched_group_barrier(0x100, 6, 0);   // DS_READ x6 (tap 0)
      #pragma unroll
      for (int tap = 0; tap < 9; ++tap) {
        const int cur = tap & 1, nxt = cur ^ 1;
        if (tap < 8) LOADTAP(tap + 1, nxt);   // issue next-tap reads FIRST
        if (tap < 8)
          __builtin_amdgcn_sched_group_barrier(0x100, 6, 0);  // DS_READ x6 (t+1)
        #pragma unroll
        for (int bt = 0; bt < 4; ++bt) {
          acc[0][bt] = __builtin_amdgcn_mfma_i32_32x32x32_i8(fa0[cur], fb[cur][bt], acc[0][bt], 0, 0, 0);
          acc[1][bt] = __builtin_amdgcn_mfma_i32_32x32x32_i8(fa1[cur], fb[cur][bt], acc[1][bt], 0, 0, 0);
        }
        __builtin_amdgcn_sched_group_barrier(0x008, 8, 0);    // MFMA x8 (tap t)
      }
    }
    buf ^= 1;
  }

  const int h = h0 + 2 * wv + (n >> 4);   // <= 55 always
  const int wbase = lane & 15;
  #pragma unroll
  for (int ct = 0; ct < 2; ++ct) {
    #pragma unroll
    for (int r = 0; r < 16; ++r) {
      const int co64 = ct * 32 + (r & 3) + 8 * (r >> 2) + 4 * gq;
      const int bv = bls[co64];
      int* orow = out + ((b * 256 + tc * 64 + co64) * 56 + h) * 56;
      #pragma unroll
      for (int bt = 0; bt < 4; ++bt) {
        const int w0 = bt * 16 + wbase;
        if (w0 < 56) orow[w0] = acc[ct][bt][r] + bv;
      }
    }
  }
}

extern "C" void kernel_launch(void* const* d_in, const int* in_sizes, int n_in,
                              void* d_out, int out_size, void* d_ws, size_t ws_size,
                              hipStream_t stream) {
  const int* x    = (const int*)d_in[0];
  const int* w    = (const int*)d_in[1];
  const int* bias = (const int*)d_in[2];
  unsigned char* ws8 = (unsigned char*)d_ws;   // x8 then w8 (~14.4 MB)
  hipLaunchKernelGGL(pack_all, dim3(1156), dim3(256), 0, stream, x, w, ws8);
  hipLaunchKernelGGL(conv_main, dim3(112, 4, 1), dim3(256), 0, stream,
                     ws8, bias, (int*)d_out);
}